// Round 1
// baseline (116.961 us; speedup 1.0000x reference)
//
#include <hip/hip_runtime.h>
#include <math.h>

// Problem constants (fixed by the reference's setup_inputs)
#define BB 32
#define LL 40
#define HH 448
#define SS 8000
#define NC 25
#define H4 (HH / 4)   // 112 float4 per row

// ---------------- Kernel 1: x_pool[b,k] = sum_{l,h} x[b,l,h] * W[k,h] ----------------
__global__ void pool_kernel(const float* __restrict__ x,
                            const float* __restrict__ W,
                            float* __restrict__ xpool) {
    __shared__ float xsum[HH];
    const int b = blockIdx.x;
    const int tid = threadIdx.x;
    const float* xb = x + (size_t)b * LL * HH;

    // Phase 1: pool over L (coalesced: consecutive threads -> consecutive h)
    for (int h = tid; h < HH; h += blockDim.x) {
        float s = 0.f;
        #pragma unroll 8
        for (int l = 0; l < LL; ++l) s += xb[(size_t)l * HH + h];
        xsum[h] = s;
    }
    __syncthreads();

    // Phase 2: dot xsum with row k of W (float4 loads; xsum reads are
    // wave-uniform -> LDS broadcast, conflict-free)
    for (int k = tid; k < HH; k += blockDim.x) {
        const float4* wr = (const float4*)(W + (size_t)k * HH);
        float acc = 0.f;
        #pragma unroll 4
        for (int h4 = 0; h4 < H4; ++h4) {
            float4 w4 = wr[h4];
            acc += xsum[h4 * 4 + 0] * w4.x;
            acc += xsum[h4 * 4 + 1] * w4.y;
            acc += xsum[h4 * 4 + 2] * w4.z;
            acc += xsum[h4 * 4 + 3] * w4.w;
        }
        xpool[b * HH + k] = acc;
    }
}

// ---------------- Kernel 2: one wave per segment; scores + online softmax ----------------
__global__ __launch_bounds__(256) void score_kernel(
        const float* __restrict__ cand,
        const float* __restrict__ xpool,
        const int* __restrict__ batch_idx,
        const int* __restrict__ label_in_seg,
        float* __restrict__ seg_loss,
        float* __restrict__ seg_acc) {
    const int wave = threadIdx.x >> 6;
    const int lane = threadIdx.x & 63;
    const int seg = blockIdx.x * 4 + wave;
    if (seg >= SS) return;

    const int label = label_in_seg[seg];
    const long t0 = (long)seg * NC;

    float m = -INFINITY;
    float ssum = 0.f;
    float label_score = 0.f;

    for (int c = 0; c < NC; ++c) {
        const long t = t0 + c;
        const int bi = batch_idx[t];
        const float4* cr = (const float4*)(cand + t * (long)HH);
        const float4* xr = (const float4*)(xpool + bi * HH);

        // 112 float4 covered by: lane (all 64) + 64+lane (lanes < 48)
        float4 a = cr[lane];
        float4 b = xr[lane];
        float p = a.x * b.x + a.y * b.y + a.z * b.z + a.w * b.w;
        if (lane < 48) {
            float4 a2 = cr[64 + lane];
            float4 b2 = xr[64 + lane];
            p += a2.x * b2.x + a2.y * b2.y + a2.z * b2.z + a2.w * b2.w;
        }

        // 64-lane butterfly: every lane ends with the full dot
        #pragma unroll
        for (int off = 32; off > 0; off >>= 1) p += __shfl_xor(p, off, 64);

        const float score = p;
        if (c == label) label_score = score;
        const float nm = fmaxf(m, score);
        ssum = ssum * __expf(m - nm) + __expf(score - nm);
        m = nm;
    }

    if (lane == 0) {
        const float lse = m + __logf(ssum);
        seg_loss[seg] = lse - label_score;
        seg_acc[seg] = (label_score >= m) ? 1.f : 0.f;
    }
}

// ---------------- Kernel 3: deterministic fixed-order final reduction ----------------
__global__ void reduce_kernel(const float* __restrict__ seg_loss,
                              const float* __restrict__ seg_acc,
                              float* __restrict__ out) {
    __shared__ float sl[256];
    __shared__ float sa[256];
    const int tid = threadIdx.x;
    float l = 0.f, a = 0.f;
    for (int s = tid; s < SS; s += 256) {
        l += seg_loss[s];
        a += seg_acc[s];
    }
    sl[tid] = l;
    sa[tid] = a;
    __syncthreads();
    for (int off = 128; off > 0; off >>= 1) {
        if (tid < off) {
            sl[tid] += sl[tid + off];
            sa[tid] += sa[tid + off];
        }
        __syncthreads();
    }
    if (tid == 0) {
        out[0] = sl[0] / (float)BB;   // loss = sum(lse - label_score) / nbatch
        out[1] = sa[0] / (float)SS;   // acc  = mean(label >= seg_max)
    }
}

extern "C" void kernel_launch(void* const* d_in, const int* in_sizes, int n_in,
                              void* d_out, int out_size, void* d_ws, size_t ws_size,
                              hipStream_t stream) {
    const float* x_mol   = (const float*)d_in[0];   // [32,40,448] f32
    const float* cand    = (const float*)d_in[1];   // [200000,448] f32
    const float* W       = (const float*)d_in[2];   // [448,448] f32
    const int*   bidx    = (const int*)d_in[3];     // [200000] i32
    const int*   label   = (const int*)d_in[4];     // [8000] i32
    float* out = (float*)d_out;                     // [loss, acc]

    // Workspace layout (floats): xpool[32*448] | seg_loss[8000] | seg_acc[8000]
    float* ws       = (float*)d_ws;
    float* xpool    = ws;                 // 14336 floats
    float* seg_loss = ws + BB * HH;       // 8000 floats
    float* seg_acc  = seg_loss + SS;      // 8000 floats
    // total 121,344 bytes — well under ws_size

    pool_kernel<<<BB, 256, 0, stream>>>(x_mol, W, xpool);
    score_kernel<<<SS / 4, 256, 0, stream>>>(cand, xpool, bidx, label,
                                             seg_loss, seg_acc);
    reduce_kernel<<<1, 256, 0, stream>>>(seg_loss, seg_acc, out);
}

// Round 3
// 75.817 us; speedup vs baseline: 1.5427x; 1.5427x over previous
//
#include <hip/hip_runtime.h>
#include <math.h>

// Problem constants (fixed by the reference's setup_inputs)
#define BB 32
#define LL 40
#define HH 448
#define SS 8000
#define NC 25
#define H4 (HH / 4)     // 112 float4 per row
#define NBLK (SS / 4)   // 2000 score blocks, 4 waves (segments) each

// Native Clang vector (works with __builtin_nontemporal_load, unlike HIP float4)
typedef float f4 __attribute__((ext_vector_type(4)));

// ---------------- Kernel 1: x_pool[b,k] = sum_{l,h} x[b,l,h] * W[k,h] ----------------
// grid: (BB, 7). Each block: phase-1 pools x[b] over L (redundant across the 7
// k-chunk blocks — 71 KB of L2-hot reads each, free), phase-2 computes 64 k
// values with a quarter-wave (4 lanes) per k.
__global__ __launch_bounds__(256) void pool_kernel(const float* __restrict__ x,
                                                   const float* __restrict__ W,
                                                   float* __restrict__ xpool) {
    __shared__ float xsum[HH];
    const int b = blockIdx.x;
    const int kc = blockIdx.y;
    const int tid = threadIdx.x;
    const float* xb = x + (size_t)b * LL * HH;

    // Phase 1: pool over L (coalesced: consecutive threads -> consecutive h)
    for (int h = tid; h < HH; h += 256) {
        float s = 0.f;
        #pragma unroll 8
        for (int l = 0; l < LL; ++l) s += xb[(size_t)l * HH + h];
        xsum[h] = s;
    }
    __syncthreads();

    // Phase 2: 64 k-values per block; 4 lanes cooperate on each k.
    const int kk  = tid >> 2;          // 0..63  (k within chunk)
    const int sub = tid & 3;           // 0..3   (lane within quad)
    const int k   = kc * 64 + kk;
    const f4* wr = (const f4*)(W + (size_t)k * HH);
    float acc = 0.f;
    #pragma unroll 7
    for (int j = sub; j < H4; j += 4) {
        f4 w4 = wr[j];
        acc += xsum[j * 4 + 0] * w4.x;
        acc += xsum[j * 4 + 1] * w4.y;
        acc += xsum[j * 4 + 2] * w4.z;
        acc += xsum[j * 4 + 3] * w4.w;
    }
    // reduce across the quad (lanes sub=0..3)
    acc += __shfl_xor(acc, 1, 64);
    acc += __shfl_xor(acc, 2, 64);
    if (sub == 0) xpool[b * HH + k] = acc;
}

// ---------------- Kernel 2: one wave per segment; scores + online softmax ----------------
__global__ __launch_bounds__(256) void score_kernel(
        const float* __restrict__ cand,
        const float* __restrict__ xpool,
        const int* __restrict__ batch_idx,
        const int* __restrict__ label_in_seg,
        float* __restrict__ blk_loss,
        float* __restrict__ blk_acc) {
    __shared__ float s_loss[4];
    __shared__ float s_acc[4];
    const int wave = threadIdx.x >> 6;
    const int lane = threadIdx.x & 63;
    const int seg = blockIdx.x * 4 + wave;   // SS = 4 * gridDim.x exactly

    const int label = label_in_seg[seg];
    const long t0 = (long)seg * NC;

    float m = -INFINITY;
    float ssum = 0.f;
    float label_score = 0.f;

    for (int c = 0; c < NC; ++c) {
        const long t = t0 + c;
        const int bi = batch_idx[t];
        const f4* cr = (const f4*)(cand + t * (long)HH);
        const f4* xr = (const f4*)(xpool + bi * HH);

        // 112 float4 covered by: lane (all 64) + 64+lane (lanes < 48)
        f4 a = __builtin_nontemporal_load(cr + lane);   // streamed once
        f4 b = xr[lane];                                // L2-hot
        float p = a.x * b.x + a.y * b.y + a.z * b.z + a.w * b.w;
        if (lane < 48) {
            f4 a2 = __builtin_nontemporal_load(cr + 64 + lane);
            f4 b2 = xr[64 + lane];
            p += a2.x * b2.x + a2.y * b2.y + a2.z * b2.z + a2.w * b2.w;
        }

        // 64-lane butterfly: every lane ends with the full dot
        #pragma unroll
        for (int off = 32; off > 0; off >>= 1) p += __shfl_xor(p, off, 64);

        const float score = p;
        if (c == label) label_score = score;
        const float nm = fmaxf(m, score);
        ssum = ssum * __expf(m - nm) + __expf(score - nm);
        m = nm;
    }

    if (lane == 0) {
        const float lse = m + __logf(ssum);
        s_loss[wave] = lse - label_score;
        s_acc[wave] = (label_score >= m) ? 1.f : 0.f;
    }
    __syncthreads();
    if (threadIdx.x == 0) {
        blk_loss[blockIdx.x] = (s_loss[0] + s_loss[1]) + (s_loss[2] + s_loss[3]);
        blk_acc[blockIdx.x]  = (s_acc[0] + s_acc[1]) + (s_acc[2] + s_acc[3]);
    }
}

// ---------------- Kernel 3: deterministic fixed-order final reduction ----------------
__global__ __launch_bounds__(256) void reduce_kernel(const float* __restrict__ blk_loss,
                                                     const float* __restrict__ blk_acc,
                                                     float* __restrict__ out) {
    __shared__ float sl[256];
    __shared__ float sa[256];
    const int tid = threadIdx.x;
    float l = 0.f, a = 0.f;
    for (int s = tid; s < NBLK; s += 256) {
        l += blk_loss[s];
        a += blk_acc[s];
    }
    sl[tid] = l;
    sa[tid] = a;
    __syncthreads();
    for (int off = 128; off > 0; off >>= 1) {
        if (tid < off) {
            sl[tid] += sl[tid + off];
            sa[tid] += sa[tid + off];
        }
        __syncthreads();
    }
    if (tid == 0) {
        out[0] = sl[0] / (float)BB;   // loss = sum(lse - label_score) / nbatch
        out[1] = sa[0] / (float)SS;   // acc  = mean(label >= seg_max)
    }
}

extern "C" void kernel_launch(void* const* d_in, const int* in_sizes, int n_in,
                              void* d_out, int out_size, void* d_ws, size_t ws_size,
                              hipStream_t stream) {
    const float* x_mol   = (const float*)d_in[0];   // [32,40,448] f32
    const float* cand    = (const float*)d_in[1];   // [200000,448] f32
    const float* W       = (const float*)d_in[2];   // [448,448] f32
    const int*   bidx    = (const int*)d_in[3];     // [200000] i32
    const int*   label   = (const int*)d_in[4];     // [8000] i32
    float* out = (float*)d_out;                     // [loss, acc]

    // Workspace layout (floats): xpool[32*448] | blk_loss[2000] | blk_acc[2000]
    float* ws       = (float*)d_ws;
    float* xpool    = ws;                 // 14336 floats
    float* blk_loss = ws + BB * HH;       // 2000 floats
    float* blk_acc  = blk_loss + NBLK;    // 2000 floats

    dim3 pgrid(BB, 7);
    pool_kernel<<<pgrid, 256, 0, stream>>>(x_mol, W, xpool);
    score_kernel<<<NBLK, 256, 0, stream>>>(cand, xpool, bidx, label,
                                           blk_loss, blk_acc);
    reduce_kernel<<<1, 256, 0, stream>>>(blk_loss, blk_acc, out);
}